// Round 5
// baseline (549.594 us; speedup 1.0000x reference)
//
#include <hip/hip_runtime.h>
#include <hip/hip_fp16.h>

// GATv2 x3 + MLP head on MI355X.
// R8 = R7 with the self-loop clustering bug fixed. R7 binned self-loop edges
// (consecutive node ids) through the same sub-buckets as random edges; one
// 1024-edge block dumped 128 entries/bucket into a single class -> 400 mean
// vs 384 cap -> dropped self-loops -> absmax 0.164. Self-loops are now
// pre-seeded in k_insert (slot 0 of every node, deterministic) and k_bin
// handles only the E random edges (mean 256/sub-bucket, cap 384 = +8 sigma).

constexpr int N = 100000;
constexpr int E = 1600000;
constexpr int S = 48;       // slots per node (cap; stores guarded)

constexpr int NBUK = (N + 127) >> 7;          // 782 buckets of 128 nodes
constexpr int BCAP = 384;                     // per (bucket, class) cap; mean 256
constexpr int BIN_B = (E + 1023) / 1024;      // bin blocks (1024 edges each)
constexpr int XF_B = N / 32;                  // xform blocks (32 nodes each)

// ---------------- pass 1: bin real edges by dst bucket, XCD-class striped ---

__global__ __launch_bounds__(256) void k_bin(const int* __restrict__ ei,
                                             int* __restrict__ bcnt,
                                             unsigned* __restrict__ bbuf) {
  const int base = blockIdx.x * 1024 + threadIdx.x;
  const int cls = blockIdx.x & 7;   // maps ~1:1 to XCD by round-robin dispatch
  unsigned ent[4];
  int idx[4];
  bool ok[4];
  #pragma unroll
  for (int j = 0; j < 4; ++j) {
    int e = base + j * 256;
    ok[j] = e < E;
    int ec = ok[j] ? e : 0;
    int src = ei[ec];
    int dst = ei[E + ec];
    idx[j] = (dst >> 7) * 8 + cls;
    ent[j] = ((unsigned)(dst & 127) << 17) | (unsigned)src;  // 7b dstlo | 17b src
  }
  int pos[4];
  #pragma unroll
  for (int j = 0; j < 4; ++j) {  // 4 independent atomic chains in flight
    pos[j] = ok[j] ? atomicAdd(&bcnt[idx[j]], 1) : BCAP;
  }
  #pragma unroll
  for (int j = 0; j < 4; ++j) {
    if (pos[j] < BCAP) bbuf[(size_t)idx[j] * BCAP + pos[j]] = ent[j];
  }
}

// ---------------- pass 2: per-bucket insert with LDS slot claims ------------
// Slot 0 of every node is the (deterministic) self-loop.

__global__ __launch_bounds__(256) void k_insert(const int* __restrict__ bcnt,
                                                const unsigned* __restrict__ bbuf,
                                                int* __restrict__ deg,
                                                int* __restrict__ ebuf) {
  __shared__ int cnt[128];
  const int b = blockIdx.x;
  const int tid = threadIdx.x;
  const int node0 = b * 128 + tid;
  if (tid < 128) {
    cnt[tid] = 1;                                   // self-loop occupies slot 0
    if (node0 < N) ebuf[node0 * S] = node0;
  }
  __syncthreads();
  #pragma unroll 1
  for (int c = 0; c < 8; ++c) {
    const int n = min(bcnt[b * 8 + c], BCAP);
    const unsigned* arr = bbuf + (size_t)(b * 8 + c) * BCAP;
    for (int i = tid; i < n; i += 256) {
      const unsigned ent = arr[i];
      const int dlo = (int)(ent >> 17);
      const int src = (int)(ent & 0x1FFFFu);
      const int pos = atomicAdd(&cnt[dlo], 1);   // LDS atomic, block-exclusive
      if (pos < S) ebuf[(b * 128 + dlo) * S + pos] = src;
    }
  }
  __syncthreads();
  if (tid < 128 && node0 < N) deg[node0] = cnt[tid];
}

// ---------------- dense transform body: y[n,M] = x[n,K] @ w[K,M] + b --------
// No x staging: x reads are uniform within a node-group (L1 broadcast).

template <int K, int M, int NB>
__device__ __forceinline__ void xform_body(const float* __restrict__ x,
                                           const float* __restrict__ w,
                                           const float* __restrict__ b,
                                           __half* __restrict__ y, int blk) {
  constexpr int TPN = M / 4;       // channel threads per node group
  constexpr int NG = 256 / TPN;    // node groups per block
  constexpr int NPB = NG * NB;     // nodes per block (32)
  __shared__ float wl[K * M];
  const int tid = threadIdx.x;
  const float4* w4 = reinterpret_cast<const float4*>(w);
  float4* wl4 = reinterpret_cast<float4*>(wl);
  for (int i = tid; i < K * M / 4; i += 256) wl4[i] = w4[i];
  __syncthreads();
  const int nbase = blk * NPB;
  const int tn = tid % TPN;
  const int ng = tid / TPN;
  const float* xrow = x + (size_t)(nbase + ng * NB) * K;
  float4 acc[NB];
  const float4 bv = *reinterpret_cast<const float4*>(b + tn * 4);
  #pragma unroll
  for (int j = 0; j < NB; ++j) acc[j] = bv;
  #pragma unroll 4
  for (int k = 0; k < K; ++k) {
    float4 wv = *reinterpret_cast<const float4*>(&wl[k * M + tn * 4]);
    #pragma unroll
    for (int j = 0; j < NB; ++j) {
      float xv = xrow[j * K + k];
      acc[j].x += xv * wv.x; acc[j].y += xv * wv.y;
      acc[j].z += xv * wv.z; acc[j].w += xv * wv.w;
    }
  }
  #pragma unroll
  for (int j = 0; j < NB; ++j) {
    __half2 p0 = __float22half2_rn(make_float2(acc[j].x, acc[j].y));
    __half2 p1 = __float22half2_rn(make_float2(acc[j].z, acc[j].w));
    uint2 pk = make_uint2(__builtin_bit_cast(unsigned, p0),
                          __builtin_bit_cast(unsigned, p1));
    *reinterpret_cast<uint2*>(y + (size_t)(nbase + ng * NB + j) * M + tn * 4) = pk;
  }
}

// ---------------- fused L+R transform (all layers) ----------------

template <int K, int M, int NB>
__global__ __launch_bounds__(256) void k_xform2(const float* __restrict__ x,
                                                const float* __restrict__ wlp,
                                                const float* __restrict__ blp,
                                                const float* __restrict__ wrp,
                                                const float* __restrict__ brp,
                                                __half* __restrict__ A,
                                                __half* __restrict__ B) {
  int blk = blockIdx.x;
  const bool right = blk >= XF_B;
  const int xblk = right ? blk - XF_B : blk;
  xform_body<K, M, NB>(x, right ? wrp : wlp, right ? brp : blp,
                       right ? B : A, xblk);
}

// ---------------- GATv2 aggregation: one wave per dst node ----------------
// Lane holds 8 fp16 features = one 16B gather per edge.
// One head (32 ch) == one 4-lane quad: score reduce = 2 quad_perm DPP adds.
// EPI edges per phase (4/8/16); 2-stage decoupled pipeline.

template <int CTRL>
__device__ __forceinline__ float dpp_add(float x) {
  return x + __builtin_bit_cast(float,
      __builtin_amdgcn_update_dpp(0, __builtin_bit_cast(int, x),
                                  CTRL, 0xF, 0xF, true));
}

__device__ __forceinline__ void cvt8(const uint4 r, float4& a, float4& b) {
  float2 f;
  f = __half22float2(__builtin_bit_cast(__half2, r.x)); a.x = f.x; a.y = f.y;
  f = __half22float2(__builtin_bit_cast(__half2, r.y)); a.z = f.x; a.w = f.y;
  f = __half22float2(__builtin_bit_cast(__half2, r.z)); b.x = f.x; b.y = f.y;
  f = __half22float2(__builtin_bit_cast(__half2, r.w)); b.z = f.x; b.w = f.y;
}

template <int H>
__global__ __launch_bounds__(256) void k_gat(const __half* __restrict__ xl,
                                             const __half* __restrict__ xr,
                                             const float* __restrict__ att,
                                             const float* __restrict__ bias,
                                             const int* __restrict__ deg,
                                             const int* __restrict__ ebuf,
                                             float* __restrict__ out) {
  constexpr int F = H * 32;
  constexpr int F8 = F / 8;        // 16B chunks (8 halfs) per row
  constexpr int F4 = F / 4;        // float4 per fp32 out row
  constexpr int LPE = F8;          // lanes per edge: 16 / 8 / 4
  constexpr int EPI = 64 / LPE;    // edges per iteration: 4 / 8 / 16
  constexpr float LOG2E = 1.44269504088896f;
  const int lane = threadIdx.x & 63;
  const int node = (blockIdx.x * blockDim.x + threadIdx.x) >> 6;
  if (node >= N) return;
  const int li = lane & (LPE - 1);  // 16B chunk index within row
  const int eg = lane / LPE;

  const uint4* xl4 = reinterpret_cast<const uint4*>(xl);
  const uint4* xr4 = reinterpret_cast<const uint4*>(xr);

  float4 xi0, xi1;
  cvt8(xr4[(unsigned)node * F8 + li], xi0, xi1);
  float4 at0 = reinterpret_cast<const float4*>(att)[li * 2];
  float4 at1 = reinterpret_cast<const float4*>(att)[li * 2 + 1];
  at0.x *= LOG2E; at0.y *= LOG2E; at0.z *= LOG2E; at0.w *= LOG2E;
  at1.x *= LOG2E; at1.y *= LOG2E; at1.z *= LOG2E; at1.w *= LOG2E;

  float4 acc0 = make_float4(0.f, 0.f, 0.f, 0.f);
  float4 acc1 = make_float4(0.f, 0.f, 0.f, 0.f);
  float l = 0.f;

  const int* row = ebuf + node * S;
  const int dn = min(deg[node], S);   // deg >= 1 (self loop)
  const int last = dn - 1;
  const int iters = (dn + EPI - 1) / EPI;

  auto process = [&](const uint4& raw, bool valid) {
    float4 j0, j1;
    cvt8(raw, j0, j1);
    float v0 = xi0.x + j0.x; v0 = fmaxf(v0, 0.2f * v0);
    float v1 = xi0.y + j0.y; v1 = fmaxf(v1, 0.2f * v1);
    float v2 = xi0.z + j0.z; v2 = fmaxf(v2, 0.2f * v2);
    float v3 = xi0.w + j0.w; v3 = fmaxf(v3, 0.2f * v3);
    float v4 = xi1.x + j1.x; v4 = fmaxf(v4, 0.2f * v4);
    float v5 = xi1.y + j1.y; v5 = fmaxf(v5, 0.2f * v5);
    float v6 = xi1.z + j1.z; v6 = fmaxf(v6, 0.2f * v6);
    float v7 = xi1.w + j1.w; v7 = fmaxf(v7, 0.2f * v7);
    float t = at0.x * v0;
    t = fmaf(at0.y, v1, t);
    t = fmaf(at0.z, v2, t);
    t = fmaf(at0.w, v3, t);
    t = fmaf(at1.x, v4, t);
    t = fmaf(at1.y, v5, t);
    t = fmaf(at1.z, v6, t);
    t = fmaf(at1.w, v7, t);
    // head = one 4-lane quad: butterfly via quad_perm DPP (VALU, no LDS pipe)
    t = dpp_add<0xB1>(t);   // xor 1: [1,0,3,2]
    t = dpp_add<0x4E>(t);   // xor 2: [2,3,0,1]
    float pm = valid ? exp2f(t) : 0.f;
    l += pm;
    acc0.x = fmaf(pm, j0.x, acc0.x); acc0.y = fmaf(pm, j0.y, acc0.y);
    acc0.z = fmaf(pm, j0.z, acc0.z); acc0.w = fmaf(pm, j0.w, acc0.w);
    acc1.x = fmaf(pm, j1.x, acc1.x); acc1.y = fmaf(pm, j1.y, acc1.y);
    acc1.z = fmaf(pm, j1.z, acc1.z); acc1.w = fmaf(pm, j1.w, acc1.w);
  };

  // pipeline warm-up: src prefetched 2 iterations ahead, gather 1 ahead
  int i = eg;
  bool vA = i < dn;
  int s0 = row[min(i, last)];
  i += EPI;
  uint4 xjA = xl4[(unsigned)s0 * F8 + li];
  bool vB = i < dn;
  int sN = row[min(i, last)];
  i += EPI;
  uint4 xjB;

  for (int it = 0; it < iters; it += 2) {
    // ---- phase A: consume (xjA, vA) = iteration it ----
    xjB = xl4[(unsigned)sN * F8 + li];             // gather it+1
    bool vn = i < dn;
    sN = row[min(i, last)];                        // src it+2
    i += EPI;
    process(xjA, vA);
    vA = vn;
    // ---- phase B: consume (xjB, vB) = iteration it+1 ----
    xjA = xl4[(unsigned)sN * F8 + li];             // gather it+2
    vn = i < dn;
    sN = row[min(i, last)];                        // src it+3
    i += EPI;
    process(xjB, vB);
    vB = vn;
  }

  // combine the EPI edge slots (once per node)
  #pragma unroll
  for (int ofs = LPE; ofs < 64; ofs <<= 1) {
    acc0.x += __shfl_xor(acc0.x, ofs);
    acc0.y += __shfl_xor(acc0.y, ofs);
    acc0.z += __shfl_xor(acc0.z, ofs);
    acc0.w += __shfl_xor(acc0.w, ofs);
    acc1.x += __shfl_xor(acc1.x, ofs);
    acc1.y += __shfl_xor(acc1.y, ofs);
    acc1.z += __shfl_xor(acc1.z, ofs);
    acc1.w += __shfl_xor(acc1.w, ofs);
    l      += __shfl_xor(l, ofs);
  }

  if (lane < LPE) {
    const float inv = 1.f / (l + 1e-16f);
    const float4 bv0 = reinterpret_cast<const float4*>(bias)[li * 2];
    const float4 bv1 = reinterpret_cast<const float4*>(bias)[li * 2 + 1];
    float4 r0, r1;
    r0.x = fmaxf(acc0.x * inv + bv0.x, 0.f);
    r0.y = fmaxf(acc0.y * inv + bv0.y, 0.f);
    r0.z = fmaxf(acc0.z * inv + bv0.z, 0.f);
    r0.w = fmaxf(acc0.w * inv + bv0.w, 0.f);
    r1.x = fmaxf(acc1.x * inv + bv1.x, 0.f);
    r1.y = fmaxf(acc1.y * inv + bv1.y, 0.f);
    r1.z = fmaxf(acc1.z * inv + bv1.z, 0.f);
    r1.w = fmaxf(acc1.w * inv + bv1.w, 0.f);
    float4* op = reinterpret_cast<float4*>(out) + (unsigned)node * F4 + li * 2;
    op[0] = r0;
    op[1] = r1;
  }
}

// ---------------- MLP head + output transforms ----------------

__global__ __launch_bounds__(256) void k_mlp(const float* __restrict__ h,
                                             const float* __restrict__ wm1,
                                             const float* __restrict__ bm1,
                                             const float* __restrict__ wm2,
                                             const float* __restrict__ bm2,
                                             float* __restrict__ out) {
  __shared__ float w1[512], b1[16], w2[32], b2[2];
  const int tid = threadIdx.x;
  for (int i = tid; i < 512; i += 256) w1[i] = wm1[i];
  if (tid < 16) b1[tid] = bm1[tid];
  if (tid < 32) w2[tid] = wm2[tid];
  if (tid < 2)  b2[tid] = bm2[tid];
  __syncthreads();
  const int node = blockIdx.x * blockDim.x + tid;
  if (node >= N) return;
  float hv[32];
  const float* hp = h + (size_t)node * 32;
  #pragma unroll
  for (int k = 0; k < 8; ++k) {
    float4 v = reinterpret_cast<const float4*>(hp)[k];
    hv[4 * k] = v.x; hv[4 * k + 1] = v.y; hv[4 * k + 2] = v.z; hv[4 * k + 3] = v.w;
  }
  float r0 = b2[0], r1 = b2[1];
  #pragma unroll
  for (int j = 0; j < 16; ++j) {
    float a = b1[j];
    #pragma unroll
    for (int k = 0; k < 32; ++k) a += hv[k] * w1[k * 16 + j];
    a = fmaxf(a, 0.f);
    r0 += a * w2[j * 2];
    r1 += a * w2[j * 2 + 1];
  }
  float vm = 1.f / (1.f + __expf(-r0)) + 0.5f;
  float va = tanhf(r1) * 180.f;
  out[(size_t)node * 2]     = vm;
  out[(size_t)node * 2 + 1] = va;
}

// ---------------- launch ----------------

extern "C" void kernel_launch(void* const* d_in, const int* in_sizes, int n_in,
                              void* d_out, int out_size, void* d_ws, size_t ws_size,
                              hipStream_t stream) {
  const float* x   = (const float*)d_in[0];
  const int*   ei  = (const int*)d_in[1];
  const float* w1l = (const float*)d_in[2];
  const float* b1l = (const float*)d_in[3];
  const float* w1r = (const float*)d_in[4];
  const float* b1r = (const float*)d_in[5];
  const float* a1  = (const float*)d_in[6];
  const float* c1  = (const float*)d_in[7];
  const float* w2l = (const float*)d_in[8];
  const float* b2l = (const float*)d_in[9];
  const float* w2r = (const float*)d_in[10];
  const float* b2r = (const float*)d_in[11];
  const float* a2  = (const float*)d_in[12];
  const float* c2  = (const float*)d_in[13];
  const float* w3l = (const float*)d_in[14];
  const float* b3l = (const float*)d_in[15];
  const float* w3r = (const float*)d_in[16];
  const float* b3r = (const float*)d_in[17];
  const float* a3  = (const float*)d_in[18];
  const float* c3  = (const float*)d_in[19];
  const float* wm1 = (const float*)d_in[20];
  const float* bm1 = (const float*)d_in[21];
  const float* wm2 = (const float*)d_in[22];
  const float* bm2 = (const float*)d_in[23];
  float* outp = (float*)d_out;
  (void)in_sizes; (void)n_in; (void)out_size; (void)ws_size;

  char* ws = (char*)d_ws;
  size_t o = 0;
  auto take = [&](size_t bytes) {
    char* p = ws + o;
    o = (o + bytes + 255) & ~(size_t)255;
    return p;
  };
  int* deg       = (int*)take((size_t)N * sizeof(int));
  int* ebuf      = (int*)take((size_t)N * S * sizeof(int));
  int* bcnt      = (int*)take((size_t)NBUK * 8 * sizeof(int));
  unsigned* bbuf = (unsigned*)take((size_t)NBUK * 8 * BCAP * sizeof(unsigned));
  __half* A      = (__half*)take((size_t)N * 128 * sizeof(__half));  // xl (fp16)
  __half* B      = (__half*)take((size_t)N * 128 * sizeof(__half));  // xr (fp16)
  float* Cb      = (float*)take((size_t)N * 128 * sizeof(float));    // h (layer out)

  // --- graph build: 2-pass binning (shared across all 3 layers) ---
  hipMemsetAsync(bcnt, 0, (size_t)NBUK * 8 * sizeof(int), stream);
  k_bin<<<BIN_B, 256, 0, stream>>>(ei, bcnt, bbuf);
  k_insert<<<NBUK, 256, 0, stream>>>(bcnt, bbuf, deg, ebuf);

  // --- layer 1: 64 -> (4 heads x 32), concat ---
  k_xform2<64, 128, 4><<<2 * XF_B, 256, 0, stream>>>(x, w1l, b1l, w1r, b1r, A, B);
  k_gat<4><<<N / 4, 256, 0, stream>>>(A, B, a1, c1, deg, ebuf, Cb);

  // --- layer 2: 128 -> (2 heads x 32), concat ---
  k_xform2<128, 64, 2><<<2 * XF_B, 256, 0, stream>>>(Cb, w2l, b2l, w2r, b2r, A, B);
  k_gat<2><<<N / 4, 256, 0, stream>>>(A, B, a2, c2, deg, ebuf, Cb);

  // --- layer 3: 64 -> (1 head x 32), mean over 1 head == identity ---
  k_xform2<64, 32, 1><<<2 * XF_B, 256, 0, stream>>>(Cb, w3l, b3l, w3r, b3r, A, B);
  k_gat<1><<<N / 4, 256, 0, stream>>>(A, B, a3, c3, deg, ebuf, Cb);

  // --- MLP head + sigmoid/tanh ---
  k_mlp<<<(N + 255) / 256, 256, 0, stream>>>(Cb, wm1, bm1, wm2, bm2, outp);
}

// Round 6
// 446.478 us; speedup vs baseline: 1.2310x; 1.2310x over previous
//
#include <hip/hip_runtime.h>
#include <hip/hip_fp16.h>

// GATv2 x3 + MLP head on MI355X.
// R9: dense transforms moved to MFMA (mfma_f32_16x16x32_f16). R8 showed
// k_xform2 latency-bound at 87us (VALU 34%, occ 38%, 0.88 TB/s) vs a ~15us
// roofline. New k_xmm: 64-node X tile (fp16, XOR-swizzled) + both
// pre-transposed fp16 weights in LDS; 4 waves x (16 rows x M cols) x {L,R};
// D staged through LDS for coalesced uint4 stores. k_wprep pre-transposes/
// swizzles weights to fp16 once. X read once per block (L+R fused).
// bin/insert/gat/mlp unchanged from R8.

constexpr int N = 100000;
constexpr int E = 1600000;
constexpr int S = 48;       // slots per node (cap; stores guarded)

constexpr int NBUK = (N + 127) >> 7;          // 782 buckets of 128 nodes
constexpr int BCAP = 384;                     // per (bucket, class) cap; mean 256
constexpr int BIN_B = (E + 1023) / 1024;      // bin blocks (1024 edges each)
constexpr int XMM_B = (N + 63) / 64;          // xmm blocks (64 nodes each)

typedef _Float16 half8_t __attribute__((ext_vector_type(8)));
typedef _Float16 half4_t __attribute__((ext_vector_type(4)));
typedef float f32x4 __attribute__((ext_vector_type(4)));

// ---------------- pass 1: bin real edges by dst bucket, XCD-class striped ---

__global__ __launch_bounds__(256) void k_bin(const int* __restrict__ ei,
                                             int* __restrict__ bcnt,
                                             unsigned* __restrict__ bbuf) {
  const int base = blockIdx.x * 1024 + threadIdx.x;
  const int cls = blockIdx.x & 7;   // maps ~1:1 to XCD by round-robin dispatch
  unsigned ent[4];
  int idx[4];
  bool ok[4];
  #pragma unroll
  for (int j = 0; j < 4; ++j) {
    int e = base + j * 256;
    ok[j] = e < E;
    int ec = ok[j] ? e : 0;
    int src = ei[ec];
    int dst = ei[E + ec];
    idx[j] = (dst >> 7) * 8 + cls;
    ent[j] = ((unsigned)(dst & 127) << 17) | (unsigned)src;  // 7b dstlo | 17b src
  }
  int pos[4];
  #pragma unroll
  for (int j = 0; j < 4; ++j) {  // 4 independent atomic chains in flight
    pos[j] = ok[j] ? atomicAdd(&bcnt[idx[j]], 1) : BCAP;
  }
  #pragma unroll
  for (int j = 0; j < 4; ++j) {
    if (pos[j] < BCAP) bbuf[(size_t)idx[j] * BCAP + pos[j]] = ent[j];
  }
}

// ---------------- pass 2: per-bucket insert with LDS slot claims ------------
// Slot 0 of every node is the (deterministic) self-loop.

__global__ __launch_bounds__(256) void k_insert(const int* __restrict__ bcnt,
                                                const unsigned* __restrict__ bbuf,
                                                int* __restrict__ deg,
                                                int* __restrict__ ebuf) {
  __shared__ int cnt[128];
  const int b = blockIdx.x;
  const int tid = threadIdx.x;
  const int node0 = b * 128 + tid;
  if (tid < 128) {
    cnt[tid] = 1;                                   // self-loop occupies slot 0
    if (node0 < N) ebuf[node0 * S] = node0;
  }
  __syncthreads();
  #pragma unroll 1
  for (int c = 0; c < 8; ++c) {
    const int n = min(bcnt[b * 8 + c], BCAP);
    const unsigned* arr = bbuf + (size_t)(b * 8 + c) * BCAP;
    for (int i = tid; i < n; i += 256) {
      const unsigned ent = arr[i];
      const int dlo = (int)(ent >> 17);
      const int src = (int)(ent & 0x1FFFFu);
      const int pos = atomicAdd(&cnt[dlo], 1);   // LDS atomic, block-exclusive
      if (pos < S) ebuf[(b * 128 + dlo) * S + pos] = src;
    }
  }
  __syncthreads();
  if (tid < 128 && node0 < N) deg[node0] = cnt[tid];
}

// ---------------- weight prep: fp32 [K][M] -> fp16 transposed+swizzled ------
// WT[m][k] stored at m*K + (k ^ ((m&7)<<3))   (XOR on 8-half units = 16B)

template <int K, int M>
__device__ __forceinline__ void wprep_body(const float* __restrict__ src,
                                           __half* __restrict__ dst, int blk) {
  const int idx = blk * 256 + threadIdx.x;     // grid sized so idx < K*M
  const int k = idx / M;
  const int m = idx % M;
  ((_Float16*)dst)[m * K + (k ^ ((m & 7) << 3))] = (_Float16)src[idx];
}

__global__ __launch_bounds__(256) void k_wprep(
    const float* w1l, const float* w1r, const float* w2l, const float* w2r,
    const float* w3l, const float* w3r,
    __half* o1l, __half* o1r, __half* o2l, __half* o2r,
    __half* o3l, __half* o3r) {
  int b = blockIdx.x;                 // sizes: 4x32 blocks (8192) + 2x8 (2048)
  if      (b < 32)  wprep_body<64, 128>(w1l, o1l, b);
  else if (b < 64)  wprep_body<64, 128>(w1r, o1r, b - 32);
  else if (b < 96)  wprep_body<128, 64>(w2l, o2l, b - 64);
  else if (b < 128) wprep_body<128, 64>(w2r, o2r, b - 96);
  else if (b < 136) wprep_body<64, 32>(w3l, o3l, b - 128);
  else              wprep_body<64, 32>(w3r, o3r, b - 136);
}

// ---------------- MFMA transform: y = x[K] @ w[K,M] + b, L and R fused ------
// Block: 64 nodes, 4 waves; wave = 16 rows x M cols. fp16 in, fp32 acc,
// fp16 out. A: row=lane&15, k=(lane>>4)*8+j. B: col=lane&15 (from WT[M][K]).
// D: col=lane&15, row=(lane>>4)*4+r.

template <int K, int M>
__global__ __launch_bounds__(256) void k_xmm(const float* __restrict__ x,
                                             const __half* __restrict__ wtl,
                                             const __half* __restrict__ wtr,
                                             const float* __restrict__ bl,
                                             const float* __restrict__ br,
                                             __half* __restrict__ Aout,
                                             __half* __restrict__ Bout) {
  constexpr int XSZ = 64 * K;        // halfs
  constexpr int WSZ = M * K;         // halfs per weight matrix
  constexpr int KS = K / 32;         // MFMA k-steps
  constexpr int CT = M / 16;         // col tiles
  __shared__ _Float16 pool[XSZ + 2 * WSZ];

  const int tid = threadIdx.x;
  const int node0 = blockIdx.x * 64;

  // --- stage X tile (fp32 -> fp16, swizzled) ---
  for (int i = tid; i < 64 * (K / 4); i += 256) {
    const int row = i / (K / 4);
    const int c4 = i % (K / 4);
    const int grow = min(node0 + row, N - 1);
    float4 v = reinterpret_cast<const float4*>(x)[(size_t)grow * (K / 4) + c4];
    const int k0 = c4 * 4;
    const int hidx = row * K + ((k0) ^ ((row & 7) << 3));
    *reinterpret_cast<half4_t*>(&pool[hidx]) =
        (half4_t){(_Float16)v.x, (_Float16)v.y, (_Float16)v.z, (_Float16)v.w};
  }
  // --- stage WT_l, WT_r (linear fp16 copy; already transposed+swizzled) ---
  for (int i = tid; i < WSZ / 8; i += 256) {
    reinterpret_cast<uint4*>(&pool[XSZ])[i] =
        reinterpret_cast<const uint4*>(wtl)[i];
    reinterpret_cast<uint4*>(&pool[XSZ + WSZ])[i] =
        reinterpret_cast<const uint4*>(wtr)[i];
  }
  __syncthreads();

  const int lane = tid & 63;
  const int wid = tid >> 6;
  const int r0 = wid * 16;

  // --- A fragments (shared across col tiles and both sides) ---
  half8_t af[KS];
  #pragma unroll
  for (int ks = 0; ks < KS; ++ks) {
    const int row = r0 + (lane & 15);
    const int k0 = ks * 32 + (lane >> 4) * 8;
    af[ks] = *reinterpret_cast<const half8_t*>(
        &pool[row * K + (k0 ^ ((row & 7) << 3))]);
  }

  f32x4 accl[CT], accr[CT];
  #pragma unroll
  for (int ct = 0; ct < CT; ++ct) {
    accl[ct] = (f32x4){0.f, 0.f, 0.f, 0.f};
    accr[ct] = (f32x4){0.f, 0.f, 0.f, 0.f};
  }

  #pragma unroll
  for (int ct = 0; ct < CT; ++ct) {
    #pragma unroll
    for (int ks = 0; ks < KS; ++ks) {
      const int col = ct * 16 + (lane & 15);
      const int k0 = ks * 32 + (lane >> 4) * 8;
      const int hb = col * K + (k0 ^ ((col & 7) << 3));
      half8_t bfl = *reinterpret_cast<const half8_t*>(&pool[XSZ + hb]);
      accl[ct] = __builtin_amdgcn_mfma_f32_16x16x32_f16(af[ks], bfl, accl[ct], 0, 0, 0);
      half8_t bfr = *reinterpret_cast<const half8_t*>(&pool[XSZ + WSZ + hb]);
      accr[ct] = __builtin_amdgcn_mfma_f32_16x16x32_f16(af[ks], bfr, accr[ct], 0, 0, 0);
    }
  }

  // --- epilogue: D -> LDS (unswizzled) -> coalesced global stores ---
  __syncthreads();   // staging regions dead; D region aliases pool[0..64*M)
  #pragma unroll
  for (int ct = 0; ct < CT; ++ct) {
    const int col = ct * 16 + (lane & 15);
    const float bb = bl[col];
    #pragma unroll
    for (int r = 0; r < 4; ++r) {
      const int row = r0 + (lane >> 4) * 4 + r;
      pool[row * M + col] = (_Float16)(accl[ct][r] + bb);
    }
  }
  __syncthreads();
  for (int i = tid; i < 64 * (M / 8); i += 256) {
    const int row = i / (M / 8);
    const int j = i % (M / 8);
    const int g = node0 + row;
    if (g < N)
      reinterpret_cast<uint4*>(Aout + (size_t)g * M)[j] =
          reinterpret_cast<uint4*>(&pool[row * M])[j];
  }
  __syncthreads();
  #pragma unroll
  for (int ct = 0; ct < CT; ++ct) {
    const int col = ct * 16 + (lane & 15);
    const float bb = br[col];
    #pragma unroll
    for (int r = 0; r < 4; ++r) {
      const int row = r0 + (lane >> 4) * 4 + r;
      pool[row * M + col] = (_Float16)(accr[ct][r] + bb);
    }
  }
  __syncthreads();
  for (int i = tid; i < 64 * (M / 8); i += 256) {
    const int row = i / (M / 8);
    const int j = i % (M / 8);
    const int g = node0 + row;
    if (g < N)
      reinterpret_cast<uint4*>(Bout + (size_t)g * M)[j] =
          reinterpret_cast<uint4*>(&pool[row * M])[j];
  }
}

// ---------------- GATv2 aggregation: one wave per dst node ----------------
// Lane holds 8 fp16 features = one 16B gather per edge.
// One head (32 ch) == one 4-lane quad: score reduce = 2 quad_perm DPP adds.
// EPI edges per phase (4/8/16); 2-stage decoupled pipeline.

template <int CTRL>
__device__ __forceinline__ float dpp_add(float x) {
  return x + __builtin_bit_cast(float,
      __builtin_amdgcn_update_dpp(0, __builtin_bit_cast(int, x),
                                  CTRL, 0xF, 0xF, true));
}

__device__ __forceinline__ void cvt8(const uint4 r, float4& a, float4& b) {
  float2 f;
  f = __half22float2(__builtin_bit_cast(__half2, r.x)); a.x = f.x; a.y = f.y;
  f = __half22float2(__builtin_bit_cast(__half2, r.y)); a.z = f.x; a.w = f.y;
  f = __half22float2(__builtin_bit_cast(__half2, r.z)); b.x = f.x; b.y = f.y;
  f = __half22float2(__builtin_bit_cast(__half2, r.w)); b.z = f.x; b.w = f.y;
}

template <int H>
__global__ __launch_bounds__(256) void k_gat(const __half* __restrict__ xl,
                                             const __half* __restrict__ xr,
                                             const float* __restrict__ att,
                                             const float* __restrict__ bias,
                                             const int* __restrict__ deg,
                                             const int* __restrict__ ebuf,
                                             float* __restrict__ out) {
  constexpr int F = H * 32;
  constexpr int F8 = F / 8;        // 16B chunks (8 halfs) per row
  constexpr int F4 = F / 4;        // float4 per fp32 out row
  constexpr int LPE = F8;          // lanes per edge: 16 / 8 / 4
  constexpr int EPI = 64 / LPE;    // edges per iteration: 4 / 8 / 16
  constexpr float LOG2E = 1.44269504088896f;
  const int lane = threadIdx.x & 63;
  const int node = (blockIdx.x * blockDim.x + threadIdx.x) >> 6;
  if (node >= N) return;
  const int li = lane & (LPE - 1);  // 16B chunk index within row
  const int eg = lane / LPE;

  const uint4* xl4 = reinterpret_cast<const uint4*>(xl);
  const uint4* xr4 = reinterpret_cast<const uint4*>(xr);

  float4 xi0, xi1;
  cvt8(xr4[(unsigned)node * F8 + li], xi0, xi1);
  float4 at0 = reinterpret_cast<const float4*>(att)[li * 2];
  float4 at1 = reinterpret_cast<const float4*>(att)[li * 2 + 1];
  at0.x *= LOG2E; at0.y *= LOG2E; at0.z *= LOG2E; at0.w *= LOG2E;
  at1.x *= LOG2E; at1.y *= LOG2E; at1.z *= LOG2E; at1.w *= LOG2E;

  float4 acc0 = make_float4(0.f, 0.f, 0.f, 0.f);
  float4 acc1 = make_float4(0.f, 0.f, 0.f, 0.f);
  float l = 0.f;

  const int* row = ebuf + node * S;
  const int dn = min(deg[node], S);   // deg >= 1 (self loop)
  const int last = dn - 1;
  const int iters = (dn + EPI - 1) / EPI;

  auto process = [&](const uint4& raw, bool valid) {
    float4 j0, j1;
    cvt8(raw, j0, j1);
    float v0 = xi0.x + j0.x; v0 = fmaxf(v0, 0.2f * v0);
    float v1 = xi0.y + j0.y; v1 = fmaxf(v1, 0.2f * v1);
    float v2 = xi0.z + j0.z; v2 = fmaxf(v2, 0.2f * v2);
    float v3 = xi0.w + j0.w; v3 = fmaxf(v3, 0.2f * v3);
    float v4 = xi1.x + j1.x; v4 = fmaxf(v4, 0.2f * v4);
    float v5 = xi1.y + j1.y; v5 = fmaxf(v5, 0.2f * v5);
    float v6 = xi1.z + j1.z; v6 = fmaxf(v6, 0.2f * v6);
    float v7 = xi1.w + j1.w; v7 = fmaxf(v7, 0.2f * v7);
    float t = at0.x * v0;
    t = fmaf(at0.y, v1, t);
    t = fmaf(at0.z, v2, t);
    t = fmaf(at0.w, v3, t);
    t = fmaf(at1.x, v4, t);
    t = fmaf(at1.y, v5, t);
    t = fmaf(at1.z, v6, t);
    t = fmaf(at1.w, v7, t);
    // head = one 4-lane quad: butterfly via quad_perm DPP (VALU, no LDS pipe)
    t = dpp_add<0xB1>(t);   // xor 1: [1,0,3,2]
    t = dpp_add<0x4E>(t);   // xor 2: [2,3,0,1]
    float pm = valid ? exp2f(t) : 0.f;
    l += pm;
    acc0.x = fmaf(pm, j0.x, acc0.x); acc0.y = fmaf(pm, j0.y, acc0.y);
    acc0.z = fmaf(pm, j0.z, acc0.z); acc0.w = fmaf(pm, j0.w, acc0.w);
    acc1.x = fmaf(pm, j1.x, acc1.x); acc1.y = fmaf(pm, j1.y, acc1.y);
    acc1.z = fmaf(pm, j1.z, acc1.z); acc1.w = fmaf(pm, j1.w, acc1.w);
  };

  // pipeline warm-up: src prefetched 2 iterations ahead, gather 1 ahead
  int i = eg;
  bool vA = i < dn;
  int s0 = row[min(i, last)];
  i += EPI;
  uint4 xjA = xl4[(unsigned)s0 * F8 + li];
  bool vB = i < dn;
  int sN = row[min(i, last)];
  i += EPI;
  uint4 xjB;

  for (int it = 0; it < iters; it += 2) {
    // ---- phase A: consume (xjA, vA) = iteration it ----
    xjB = xl4[(unsigned)sN * F8 + li];             // gather it+1
    bool vn = i < dn;
    sN = row[min(i, last)];                        // src it+2
    i += EPI;
    process(xjA, vA);
    vA = vn;
    // ---- phase B: consume (xjB, vB) = iteration it+1 ----
    xjA = xl4[(unsigned)sN * F8 + li];             // gather it+2
    vn = i < dn;
    sN = row[min(i, last)];                        // src it+3
    i += EPI;
    process(xjB, vB);
    vB = vn;
  }

  // combine the EPI edge slots (once per node)
  #pragma unroll
  for (int ofs = LPE; ofs < 64; ofs <<= 1) {
    acc0.x += __shfl_xor(acc0.x, ofs);
    acc0.y += __shfl_xor(acc0.y, ofs);
    acc0.z += __shfl_xor(acc0.z, ofs);
    acc0.w += __shfl_xor(acc0.w, ofs);
    acc1.x += __shfl_xor(acc1.x, ofs);
    acc1.y += __shfl_xor(acc1.y, ofs);
    acc1.z += __shfl_xor(acc1.z, ofs);
    acc1.w += __shfl_xor(acc1.w, ofs);
    l      += __shfl_xor(l, ofs);
  }

  if (lane < LPE) {
    const float inv = 1.f / (l + 1e-16f);
    const float4 bv0 = reinterpret_cast<const float4*>(bias)[li * 2];
    const float4 bv1 = reinterpret_cast<const float4*>(bias)[li * 2 + 1];
    float4 r0, r1;
    r0.x = fmaxf(acc0.x * inv + bv0.x, 0.f);
    r0.y = fmaxf(acc0.y * inv + bv0.y, 0.f);
    r0.z = fmaxf(acc0.z * inv + bv0.z, 0.f);
    r0.w = fmaxf(acc0.w * inv + bv0.w, 0.f);
    r1.x = fmaxf(acc1.x * inv + bv1.x, 0.f);
    r1.y = fmaxf(acc1.y * inv + bv1.y, 0.f);
    r1.z = fmaxf(acc1.z * inv + bv1.z, 0.f);
    r1.w = fmaxf(acc1.w * inv + bv1.w, 0.f);
    float4* op = reinterpret_cast<float4*>(out) + (unsigned)node * F4 + li * 2;
    op[0] = r0;
    op[1] = r1;
  }
}

// ---------------- MLP head + output transforms ----------------

__global__ __launch_bounds__(256) void k_mlp(const float* __restrict__ h,
                                             const float* __restrict__ wm1,
                                             const float* __restrict__ bm1,
                                             const float* __restrict__ wm2,
                                             const float* __restrict__ bm2,
                                             float* __restrict__ out) {
  __shared__ float w1[512], b1[16], w2[32], b2[2];
  const int tid = threadIdx.x;
  for (int i = tid; i < 512; i += 256) w1[i] = wm1[i];
  if (tid < 16) b1[tid] = bm1[tid];
  if (tid < 32) w2[tid] = wm2[tid];
  if (tid < 2)  b2[tid] = bm2[tid];
  __syncthreads();
  const int node = blockIdx.x * blockDim.x + tid;
  if (node >= N) return;
  float hv[32];
  const float* hp = h + (size_t)node * 32;
  #pragma unroll
  for (int k = 0; k < 8; ++k) {
    float4 v = reinterpret_cast<const float4*>(hp)[k];
    hv[4 * k] = v.x; hv[4 * k + 1] = v.y; hv[4 * k + 2] = v.z; hv[4 * k + 3] = v.w;
  }
  float r0 = b2[0], r1 = b2[1];
  #pragma unroll
  for (int j = 0; j < 16; ++j) {
    float a = b1[j];
    #pragma unroll
    for (int k = 0; k < 32; ++k) a += hv[k] * w1[k * 16 + j];
    a = fmaxf(a, 0.f);
    r0 += a * w2[j * 2];
    r1 += a * w2[j * 2 + 1];
  }
  float vm = 1.f / (1.f + __expf(-r0)) + 0.5f;
  float va = tanhf(r1) * 180.f;
  out[(size_t)node * 2]     = vm;
  out[(size_t)node * 2 + 1] = va;
}

// ---------------- launch ----------------

extern "C" void kernel_launch(void* const* d_in, const int* in_sizes, int n_in,
                              void* d_out, int out_size, void* d_ws, size_t ws_size,
                              hipStream_t stream) {
  const float* x   = (const float*)d_in[0];
  const int*   ei  = (const int*)d_in[1];
  const float* w1l = (const float*)d_in[2];
  const float* b1l = (const float*)d_in[3];
  const float* w1r = (const float*)d_in[4];
  const float* b1r = (const float*)d_in[5];
  const float* a1  = (const float*)d_in[6];
  const float* c1  = (const float*)d_in[7];
  const float* w2l = (const float*)d_in[8];
  const float* b2l = (const float*)d_in[9];
  const float* w2r = (const float*)d_in[10];
  const float* b2r = (const float*)d_in[11];
  const float* a2  = (const float*)d_in[12];
  const float* c2  = (const float*)d_in[13];
  const float* w3l = (const float*)d_in[14];
  const float* b3l = (const float*)d_in[15];
  const float* w3r = (const float*)d_in[16];
  const float* b3r = (const float*)d_in[17];
  const float* a3  = (const float*)d_in[18];
  const float* c3  = (const float*)d_in[19];
  const float* wm1 = (const float*)d_in[20];
  const float* bm1 = (const float*)d_in[21];
  const float* wm2 = (const float*)d_in[22];
  const float* bm2 = (const float*)d_in[23];
  float* outp = (float*)d_out;
  (void)in_sizes; (void)n_in; (void)out_size; (void)ws_size;

  char* ws = (char*)d_ws;
  size_t o = 0;
  auto take = [&](size_t bytes) {
    char* p = ws + o;
    o = (o + bytes + 255) & ~(size_t)255;
    return p;
  };
  int* deg       = (int*)take((size_t)N * sizeof(int));
  int* ebuf      = (int*)take((size_t)N * S * sizeof(int));
  int* bcnt      = (int*)take((size_t)NBUK * 8 * sizeof(int));
  unsigned* bbuf = (unsigned*)take((size_t)NBUK * 8 * BCAP * sizeof(unsigned));
  __half* A      = (__half*)take((size_t)N * 128 * sizeof(__half));  // xl (fp16)
  __half* B      = (__half*)take((size_t)N * 128 * sizeof(__half));  // xr (fp16)
  float* Cb      = (float*)take((size_t)N * 128 * sizeof(float));    // h (layer out)
  __half* t1l    = (__half*)take(128 * 64 * sizeof(__half));   // WT fp16 swizzled
  __half* t1r    = (__half*)take(128 * 64 * sizeof(__half));
  __half* t2l    = (__half*)take(64 * 128 * sizeof(__half));
  __half* t2r    = (__half*)take(64 * 128 * sizeof(__half));
  __half* t3l    = (__half*)take(32 * 64 * sizeof(__half));
  __half* t3r    = (__half*)take(32 * 64 * sizeof(__half));

  // --- weight prep + graph build (shared across all 3 layers) ---
  hipMemsetAsync(bcnt, 0, (size_t)NBUK * 8 * sizeof(int), stream);
  k_wprep<<<144, 256, 0, stream>>>(w1l, w1r, w2l, w2r, w3l, w3r,
                                   t1l, t1r, t2l, t2r, t3l, t3r);
  k_bin<<<BIN_B, 256, 0, stream>>>(ei, bcnt, bbuf);
  k_insert<<<NBUK, 256, 0, stream>>>(bcnt, bbuf, deg, ebuf);

  // --- layer 1: 64 -> (4 heads x 32), concat ---
  k_xmm<64, 128><<<XMM_B, 256, 0, stream>>>(x, t1l, t1r, b1l, b1r, A, B);
  k_gat<4><<<N / 4, 256, 0, stream>>>(A, B, a1, c1, deg, ebuf, Cb);

  // --- layer 2: 128 -> (2 heads x 32), concat ---
  k_xmm<128, 64><<<XMM_B, 256, 0, stream>>>(Cb, t2l, t2r, b2l, b2r, A, B);
  k_gat<2><<<N / 4, 256, 0, stream>>>(A, B, a2, c2, deg, ebuf, Cb);

  // --- layer 3: 64 -> (1 head x 32), mean over 1 head == identity ---
  k_xmm<64, 32><<<XMM_B, 256, 0, stream>>>(Cb, t3l, t3r, b3l, b3r, A, B);
  k_gat<1><<<N / 4, 256, 0, stream>>>(A, B, a3, c3, deg, ebuf, Cb);

  // --- MLP head + sigmoid/tanh ---
  k_mlp<<<(N + 255) / 256, 256, 0, stream>>>(Cb, wm1, bm1, wm2, bm2, outp);
}

// Round 7
// 436.684 us; speedup vs baseline: 1.2586x; 1.0224x over previous
//
#include <hip/hip_runtime.h>
#include <hip/hip_fp16.h>

// GATv2 x3 + MLP head on MI355X.
// R10: k_gat inner loop moved to packed fp16 math. R9 profile: k_gat<4> is
// VALU-issue-bound (VALUBusy 86-89%, HBM 38%). Score path now 4x{v_pk_add_f16,
// v_pk_mul_f16, v_pk_max_f16, v_dot2_f32_f16} (att pre-scaled fp16), no
// converts; acc stays fp32 via mixed-precision fma (v_fma_mix codegen).
// ~55 -> ~32 wave-inst per phase. Everything else unchanged from R9.

constexpr int N = 100000;
constexpr int E = 1600000;
constexpr int S = 48;       // slots per node (cap; stores guarded)

constexpr int NBUK = (N + 127) >> 7;          // 782 buckets of 128 nodes
constexpr int BCAP = 384;                     // per (bucket, class) cap; mean 256
constexpr int BIN_B = (E + 1023) / 1024;      // bin blocks (1024 edges each)
constexpr int XMM_B = (N + 63) / 64;          // xmm blocks (64 nodes each)

typedef _Float16 half8_t __attribute__((ext_vector_type(8)));
typedef _Float16 half4_t __attribute__((ext_vector_type(4)));
typedef _Float16 h2 __attribute__((ext_vector_type(2)));
typedef float f32x4 __attribute__((ext_vector_type(4)));

// ---------------- pass 1: bin real edges by dst bucket, XCD-class striped ---

__global__ __launch_bounds__(256) void k_bin(const int* __restrict__ ei,
                                             int* __restrict__ bcnt,
                                             unsigned* __restrict__ bbuf) {
  const int base = blockIdx.x * 1024 + threadIdx.x;
  const int cls = blockIdx.x & 7;   // maps ~1:1 to XCD by round-robin dispatch
  unsigned ent[4];
  int idx[4];
  bool ok[4];
  #pragma unroll
  for (int j = 0; j < 4; ++j) {
    int e = base + j * 256;
    ok[j] = e < E;
    int ec = ok[j] ? e : 0;
    int src = ei[ec];
    int dst = ei[E + ec];
    idx[j] = (dst >> 7) * 8 + cls;
    ent[j] = ((unsigned)(dst & 127) << 17) | (unsigned)src;  // 7b dstlo | 17b src
  }
  int pos[4];
  #pragma unroll
  for (int j = 0; j < 4; ++j) {  // 4 independent atomic chains in flight
    pos[j] = ok[j] ? atomicAdd(&bcnt[idx[j]], 1) : BCAP;
  }
  #pragma unroll
  for (int j = 0; j < 4; ++j) {
    if (pos[j] < BCAP) bbuf[(size_t)idx[j] * BCAP + pos[j]] = ent[j];
  }
}

// ---------------- pass 2: per-bucket insert with LDS slot claims ------------
// Slot 0 of every node is the (deterministic) self-loop.

__global__ __launch_bounds__(256) void k_insert(const int* __restrict__ bcnt,
                                                const unsigned* __restrict__ bbuf,
                                                int* __restrict__ deg,
                                                int* __restrict__ ebuf) {
  __shared__ int cnt[128];
  const int b = blockIdx.x;
  const int tid = threadIdx.x;
  const int node0 = b * 128 + tid;
  if (tid < 128) {
    cnt[tid] = 1;                                   // self-loop occupies slot 0
    if (node0 < N) ebuf[node0 * S] = node0;
  }
  __syncthreads();
  #pragma unroll 1
  for (int c = 0; c < 8; ++c) {
    const int n = min(bcnt[b * 8 + c], BCAP);
    const unsigned* arr = bbuf + (size_t)(b * 8 + c) * BCAP;
    for (int i = tid; i < n; i += 256) {
      const unsigned ent = arr[i];
      const int dlo = (int)(ent >> 17);
      const int src = (int)(ent & 0x1FFFFu);
      const int pos = atomicAdd(&cnt[dlo], 1);   // LDS atomic, block-exclusive
      if (pos < S) ebuf[(b * 128 + dlo) * S + pos] = src;
    }
  }
  __syncthreads();
  if (tid < 128 && node0 < N) deg[node0] = cnt[tid];
}

// ---------------- weight prep: fp32 [K][M] -> fp16 transposed+swizzled ------
// WT[m][k] stored at m*K + (k ^ ((m&7)<<3))   (XOR on 8-half units = 16B)

template <int K, int M>
__device__ __forceinline__ void wprep_body(const float* __restrict__ src,
                                           __half* __restrict__ dst, int blk) {
  const int idx = blk * 256 + threadIdx.x;     // grid sized so idx < K*M
  const int k = idx / M;
  const int m = idx % M;
  ((_Float16*)dst)[m * K + (k ^ ((m & 7) << 3))] = (_Float16)src[idx];
}

__global__ __launch_bounds__(256) void k_wprep(
    const float* w1l, const float* w1r, const float* w2l, const float* w2r,
    const float* w3l, const float* w3r,
    __half* o1l, __half* o1r, __half* o2l, __half* o2r,
    __half* o3l, __half* o3r) {
  int b = blockIdx.x;                 // sizes: 4x32 blocks (8192) + 2x8 (2048)
  if      (b < 32)  wprep_body<64, 128>(w1l, o1l, b);
  else if (b < 64)  wprep_body<64, 128>(w1r, o1r, b - 32);
  else if (b < 96)  wprep_body<128, 64>(w2l, o2l, b - 64);
  else if (b < 128) wprep_body<128, 64>(w2r, o2r, b - 96);
  else if (b < 136) wprep_body<64, 32>(w3l, o3l, b - 128);
  else              wprep_body<64, 32>(w3r, o3r, b - 136);
}

// ---------------- MFMA transform: y = x[K] @ w[K,M] + b, L and R fused ------
// Block: 64 nodes, 4 waves; wave = 16 rows x M cols. fp16 in, fp32 acc,
// fp16 out. A: row=lane&15, k=(lane>>4)*8+j. B: col=lane&15 (from WT[M][K]).
// D: col=lane&15, row=(lane>>4)*4+r.

template <int K, int M>
__global__ __launch_bounds__(256) void k_xmm(const float* __restrict__ x,
                                             const __half* __restrict__ wtl,
                                             const __half* __restrict__ wtr,
                                             const float* __restrict__ bl,
                                             const float* __restrict__ br,
                                             __half* __restrict__ Aout,
                                             __half* __restrict__ Bout) {
  constexpr int XSZ = 64 * K;        // halfs
  constexpr int WSZ = M * K;         // halfs per weight matrix
  constexpr int KS = K / 32;         // MFMA k-steps
  constexpr int CT = M / 16;         // col tiles
  __shared__ _Float16 pool[XSZ + 2 * WSZ];

  const int tid = threadIdx.x;
  const int node0 = blockIdx.x * 64;

  // --- stage X tile (fp32 -> fp16, swizzled) ---
  for (int i = tid; i < 64 * (K / 4); i += 256) {
    const int row = i / (K / 4);
    const int c4 = i % (K / 4);
    const int grow = min(node0 + row, N - 1);
    float4 v = reinterpret_cast<const float4*>(x)[(size_t)grow * (K / 4) + c4];
    const int k0 = c4 * 4;
    const int hidx = row * K + ((k0) ^ ((row & 7) << 3));
    *reinterpret_cast<half4_t*>(&pool[hidx]) =
        (half4_t){(_Float16)v.x, (_Float16)v.y, (_Float16)v.z, (_Float16)v.w};
  }
  // --- stage WT_l, WT_r (linear fp16 copy; already transposed+swizzled) ---
  for (int i = tid; i < WSZ / 8; i += 256) {
    reinterpret_cast<uint4*>(&pool[XSZ])[i] =
        reinterpret_cast<const uint4*>(wtl)[i];
    reinterpret_cast<uint4*>(&pool[XSZ + WSZ])[i] =
        reinterpret_cast<const uint4*>(wtr)[i];
  }
  __syncthreads();

  const int lane = tid & 63;
  const int wid = tid >> 6;
  const int r0 = wid * 16;

  // --- A fragments (shared across col tiles and both sides) ---
  half8_t af[KS];
  #pragma unroll
  for (int ks = 0; ks < KS; ++ks) {
    const int row = r0 + (lane & 15);
    const int k0 = ks * 32 + (lane >> 4) * 8;
    af[ks] = *reinterpret_cast<const half8_t*>(
        &pool[row * K + (k0 ^ ((row & 7) << 3))]);
  }

  f32x4 accl[CT], accr[CT];
  #pragma unroll
  for (int ct = 0; ct < CT; ++ct) {
    accl[ct] = (f32x4){0.f, 0.f, 0.f, 0.f};
    accr[ct] = (f32x4){0.f, 0.f, 0.f, 0.f};
  }

  #pragma unroll
  for (int ct = 0; ct < CT; ++ct) {
    #pragma unroll
    for (int ks = 0; ks < KS; ++ks) {
      const int col = ct * 16 + (lane & 15);
      const int k0 = ks * 32 + (lane >> 4) * 8;
      const int hb = col * K + (k0 ^ ((col & 7) << 3));
      half8_t bfl = *reinterpret_cast<const half8_t*>(&pool[XSZ + hb]);
      accl[ct] = __builtin_amdgcn_mfma_f32_16x16x32_f16(af[ks], bfl, accl[ct], 0, 0, 0);
      half8_t bfr = *reinterpret_cast<const half8_t*>(&pool[XSZ + WSZ + hb]);
      accr[ct] = __builtin_amdgcn_mfma_f32_16x16x32_f16(af[ks], bfr, accr[ct], 0, 0, 0);
    }
  }

  // --- epilogue: D -> LDS (unswizzled) -> coalesced global stores ---
  __syncthreads();   // staging regions dead; D region aliases pool[0..64*M)
  #pragma unroll
  for (int ct = 0; ct < CT; ++ct) {
    const int col = ct * 16 + (lane & 15);
    const float bb = bl[col];
    #pragma unroll
    for (int r = 0; r < 4; ++r) {
      const int row = r0 + (lane >> 4) * 4 + r;
      pool[row * M + col] = (_Float16)(accl[ct][r] + bb);
    }
  }
  __syncthreads();
  for (int i = tid; i < 64 * (M / 8); i += 256) {
    const int row = i / (M / 8);
    const int j = i % (M / 8);
    const int g = node0 + row;
    if (g < N)
      reinterpret_cast<uint4*>(Aout + (size_t)g * M)[j] =
          reinterpret_cast<uint4*>(&pool[row * M])[j];
  }
  __syncthreads();
  #pragma unroll
  for (int ct = 0; ct < CT; ++ct) {
    const int col = ct * 16 + (lane & 15);
    const float bb = br[col];
    #pragma unroll
    for (int r = 0; r < 4; ++r) {
      const int row = r0 + (lane >> 4) * 4 + r;
      pool[row * M + col] = (_Float16)(accr[ct][r] + bb);
    }
  }
  __syncthreads();
  for (int i = tid; i < 64 * (M / 8); i += 256) {
    const int row = i / (M / 8);
    const int j = i % (M / 8);
    const int g = node0 + row;
    if (g < N)
      reinterpret_cast<uint4*>(Bout + (size_t)g * M)[j] =
          reinterpret_cast<uint4*>(&pool[row * M])[j];
  }
}

// ---------------- GATv2 aggregation: one wave per dst node ----------------
// Lane holds 8 fp16 features = one 16B gather per edge. Packed fp16 score
// path (pk_add/pk_mul/pk_max + v_dot2_f32_f16); fp32 accumulator via
// mixed-precision fma. One head == one 4-lane quad: reduce = 2 DPP adds.

template <int CTRL>
__device__ __forceinline__ float dpp_add(float x) {
  return x + __builtin_bit_cast(float,
      __builtin_amdgcn_update_dpp(0, __builtin_bit_cast(int, x),
                                  CTRL, 0xF, 0xF, true));
}

template <int H>
__global__ __launch_bounds__(256) void k_gat(const __half* __restrict__ xl,
                                             const __half* __restrict__ xr,
                                             const float* __restrict__ att,
                                             const float* __restrict__ bias,
                                             const int* __restrict__ deg,
                                             const int* __restrict__ ebuf,
                                             float* __restrict__ out) {
  constexpr int F = H * 32;
  constexpr int F8 = F / 8;        // 16B chunks (8 halfs) per row
  constexpr int F4 = F / 4;        // float4 per fp32 out row
  constexpr int LPE = F8;          // lanes per edge: 16 / 8 / 4
  constexpr int EPI = 64 / LPE;    // edges per iteration: 4 / 8 / 16
  constexpr float LOG2E = 1.44269504088896f;
  const int lane = threadIdx.x & 63;
  const int node = (blockIdx.x * blockDim.x + threadIdx.x) >> 6;
  if (node >= N) return;
  const int li = lane & (LPE - 1);  // 16B chunk index within row
  const int eg = lane / LPE;

  const uint4* xl4 = reinterpret_cast<const uint4*>(xl);
  const uint4* xr4 = reinterpret_cast<const uint4*>(xr);

  // xi: 8 fp16 channels kept packed
  const uint4 xiraw = xr4[(unsigned)node * F8 + li];
  h2 xi2[4];
  xi2[0] = __builtin_bit_cast(h2, xiraw.x);
  xi2[1] = __builtin_bit_cast(h2, xiraw.y);
  xi2[2] = __builtin_bit_cast(h2, xiraw.z);
  xi2[3] = __builtin_bit_cast(h2, xiraw.w);

  // att: fp32 -> pre-scaled fp16 pairs
  const float4 at0 = reinterpret_cast<const float4*>(att)[li * 2];
  const float4 at1 = reinterpret_cast<const float4*>(att)[li * 2 + 1];
  h2 at2[4];
  at2[0] = (h2){(_Float16)(at0.x * LOG2E), (_Float16)(at0.y * LOG2E)};
  at2[1] = (h2){(_Float16)(at0.z * LOG2E), (_Float16)(at0.w * LOG2E)};
  at2[2] = (h2){(_Float16)(at1.x * LOG2E), (_Float16)(at1.y * LOG2E)};
  at2[3] = (h2){(_Float16)(at1.z * LOG2E), (_Float16)(at1.w * LOG2E)};
  const h2 c02 = {(_Float16)0.2f, (_Float16)0.2f};

  float4 acc0 = make_float4(0.f, 0.f, 0.f, 0.f);
  float4 acc1 = make_float4(0.f, 0.f, 0.f, 0.f);
  float l = 0.f;

  const int* row = ebuf + node * S;
  const int dn = min(deg[node], S);   // deg >= 1 (self loop)
  const int last = dn - 1;
  const int iters = (dn + EPI - 1) / EPI;

  auto process = [&](const uint4& raw, bool valid) {
    h2 xj0 = __builtin_bit_cast(h2, raw.x);
    h2 xj1 = __builtin_bit_cast(h2, raw.y);
    h2 xj2 = __builtin_bit_cast(h2, raw.z);
    h2 xj3 = __builtin_bit_cast(h2, raw.w);
    float t = 0.f;
    h2 v;
    v = xi2[0] + xj0; v = __builtin_elementwise_max(v, v * c02);
    t = __builtin_amdgcn_fdot2(at2[0], v, t, false);
    v = xi2[1] + xj1; v = __builtin_elementwise_max(v, v * c02);
    t = __builtin_amdgcn_fdot2(at2[1], v, t, false);
    v = xi2[2] + xj2; v = __builtin_elementwise_max(v, v * c02);
    t = __builtin_amdgcn_fdot2(at2[2], v, t, false);
    v = xi2[3] + xj3; v = __builtin_elementwise_max(v, v * c02);
    t = __builtin_amdgcn_fdot2(at2[3], v, t, false);
    // head = one 4-lane quad: butterfly via quad_perm DPP (VALU, no LDS pipe)
    t = dpp_add<0xB1>(t);   // xor 1: [1,0,3,2]
    t = dpp_add<0x4E>(t);   // xor 2: [2,3,0,1]
    float pm = valid ? exp2f(t) : 0.f;
    l += pm;
    // fp32 acc; (float)h * f + acc folds to v_fma_mix_f32
    acc0.x = fmaf(pm, (float)xj0[0], acc0.x);
    acc0.y = fmaf(pm, (float)xj0[1], acc0.y);
    acc0.z = fmaf(pm, (float)xj1[0], acc0.z);
    acc0.w = fmaf(pm, (float)xj1[1], acc0.w);
    acc1.x = fmaf(pm, (float)xj2[0], acc1.x);
    acc1.y = fmaf(pm, (float)xj2[1], acc1.y);
    acc1.z = fmaf(pm, (float)xj3[0], acc1.z);
    acc1.w = fmaf(pm, (float)xj3[1], acc1.w);
  };

  // pipeline warm-up: src prefetched 2 iterations ahead, gather 1 ahead
  int i = eg;
  bool vA = i < dn;
  int s0 = row[min(i, last)];
  i += EPI;
  uint4 xjA = xl4[(unsigned)s0 * F8 + li];
  bool vB = i < dn;
  int sN = row[min(i, last)];
  i += EPI;
  uint4 xjB;

  for (int it = 0; it < iters; it += 2) {
    // ---- phase A: consume (xjA, vA) = iteration it ----
    xjB = xl4[(unsigned)sN * F8 + li];             // gather it+1
    bool vn = i < dn;
    sN = row[min(i, last)];                        // src it+2
    i += EPI;
    process(xjA, vA);
    vA = vn;
    // ---- phase B: consume (xjB, vB) = iteration it+1 ----
    xjA = xl4[(unsigned)sN * F8 + li];             // gather it+2
    vn = i < dn;
    sN = row[min(i, last)];                        // src it+3
    i += EPI;
    process(xjB, vB);
    vB = vn;
  }

  // combine the EPI edge slots (once per node)
  #pragma unroll
  for (int ofs = LPE; ofs < 64; ofs <<= 1) {
    acc0.x += __shfl_xor(acc0.x, ofs);
    acc0.y += __shfl_xor(acc0.y, ofs);
    acc0.z += __shfl_xor(acc0.z, ofs);
    acc0.w += __shfl_xor(acc0.w, ofs);
    acc1.x += __shfl_xor(acc1.x, ofs);
    acc1.y += __shfl_xor(acc1.y, ofs);
    acc1.z += __shfl_xor(acc1.z, ofs);
    acc1.w += __shfl_xor(acc1.w, ofs);
    l      += __shfl_xor(l, ofs);
  }

  if (lane < LPE) {
    const float inv = 1.f / (l + 1e-16f);
    const float4 bv0 = reinterpret_cast<const float4*>(bias)[li * 2];
    const float4 bv1 = reinterpret_cast<const float4*>(bias)[li * 2 + 1];
    float4 r0, r1;
    r0.x = fmaxf(acc0.x * inv + bv0.x, 0.f);
    r0.y = fmaxf(acc0.y * inv + bv0.y, 0.f);
    r0.z = fmaxf(acc0.z * inv + bv0.z, 0.f);
    r0.w = fmaxf(acc0.w * inv + bv0.w, 0.f);
    r1.x = fmaxf(acc1.x * inv + bv1.x, 0.f);
    r1.y = fmaxf(acc1.y * inv + bv1.y, 0.f);
    r1.z = fmaxf(acc1.z * inv + bv1.z, 0.f);
    r1.w = fmaxf(acc1.w * inv + bv1.w, 0.f);
    float4* op = reinterpret_cast<float4*>(out) + (unsigned)node * F4 + li * 2;
    op[0] = r0;
    op[1] = r1;
  }
}

// ---------------- MLP head + output transforms ----------------

__global__ __launch_bounds__(256) void k_mlp(const float* __restrict__ h,
                                             const float* __restrict__ wm1,
                                             const float* __restrict__ bm1,
                                             const float* __restrict__ wm2,
                                             const float* __restrict__ bm2,
                                             float* __restrict__ out) {
  __shared__ float w1[512], b1[16], w2[32], b2[2];
  const int tid = threadIdx.x;
  for (int i = tid; i < 512; i += 256) w1[i] = wm1[i];
  if (tid < 16) b1[tid] = bm1[tid];
  if (tid < 32) w2[tid] = wm2[tid];
  if (tid < 2)  b2[tid] = bm2[tid];
  __syncthreads();
  const int node = blockIdx.x * blockDim.x + tid;
  if (node >= N) return;
  float hv[32];
  const float* hp = h + (size_t)node * 32;
  #pragma unroll
  for (int k = 0; k < 8; ++k) {
    float4 v = reinterpret_cast<const float4*>(hp)[k];
    hv[4 * k] = v.x; hv[4 * k + 1] = v.y; hv[4 * k + 2] = v.z; hv[4 * k + 3] = v.w;
  }
  float r0 = b2[0], r1 = b2[1];
  #pragma unroll
  for (int j = 0; j < 16; ++j) {
    float a = b1[j];
    #pragma unroll
    for (int k = 0; k < 32; ++k) a += hv[k] * w1[k * 16 + j];
    a = fmaxf(a, 0.f);
    r0 += a * w2[j * 2];
    r1 += a * w2[j * 2 + 1];
  }
  float vm = 1.f / (1.f + __expf(-r0)) + 0.5f;
  float va = tanhf(r1) * 180.f;
  out[(size_t)node * 2]     = vm;
  out[(size_t)node * 2 + 1] = va;
}

// ---------------- launch ----------------

extern "C" void kernel_launch(void* const* d_in, const int* in_sizes, int n_in,
                              void* d_out, int out_size, void* d_ws, size_t ws_size,
                              hipStream_t stream) {
  const float* x   = (const float*)d_in[0];
  const int*   ei  = (const int*)d_in[1];
  const float* w1l = (const float*)d_in[2];
  const float* b1l = (const float*)d_in[3];
  const float* w1r = (const float*)d_in[4];
  const float* b1r = (const float*)d_in[5];
  const float* a1  = (const float*)d_in[6];
  const float* c1  = (const float*)d_in[7];
  const float* w2l = (const float*)d_in[8];
  const float* b2l = (const float*)d_in[9];
  const float* w2r = (const float*)d_in[10];
  const float* b2r = (const float*)d_in[11];
  const float* a2  = (const float*)d_in[12];
  const float* c2  = (const float*)d_in[13];
  const float* w3l = (const float*)d_in[14];
  const float* b3l = (const float*)d_in[15];
  const float* w3r = (const float*)d_in[16];
  const float* b3r = (const float*)d_in[17];
  const float* a3  = (const float*)d_in[18];
  const float* c3  = (const float*)d_in[19];
  const float* wm1 = (const float*)d_in[20];
  const float* bm1 = (const float*)d_in[21];
  const float* wm2 = (const float*)d_in[22];
  const float* bm2 = (const float*)d_in[23];
  float* outp = (float*)d_out;
  (void)in_sizes; (void)n_in; (void)out_size; (void)ws_size;

  char* ws = (char*)d_ws;
  size_t o = 0;
  auto take = [&](size_t bytes) {
    char* p = ws + o;
    o = (o + bytes + 255) & ~(size_t)255;
    return p;
  };
  int* deg       = (int*)take((size_t)N * sizeof(int));
  int* ebuf      = (int*)take((size_t)N * S * sizeof(int));
  int* bcnt      = (int*)take((size_t)NBUK * 8 * sizeof(int));
  unsigned* bbuf = (unsigned*)take((size_t)NBUK * 8 * BCAP * sizeof(unsigned));
  __half* A      = (__half*)take((size_t)N * 128 * sizeof(__half));  // xl (fp16)
  __half* B      = (__half*)take((size_t)N * 128 * sizeof(__half));  // xr (fp16)
  float* Cb      = (float*)take((size_t)N * 128 * sizeof(float));    // h (layer out)
  __half* t1l    = (__half*)take(128 * 64 * sizeof(__half));   // WT fp16 swizzled
  __half* t1r    = (__half*)take(128 * 64 * sizeof(__half));
  __half* t2l    = (__half*)take(64 * 128 * sizeof(__half));
  __half* t2r    = (__half*)take(64 * 128 * sizeof(__half));
  __half* t3l    = (__half*)take(32 * 64 * sizeof(__half));
  __half* t3r    = (__half*)take(32 * 64 * sizeof(__half));

  // --- weight prep + graph build (shared across all 3 layers) ---
  hipMemsetAsync(bcnt, 0, (size_t)NBUK * 8 * sizeof(int), stream);
  k_wprep<<<144, 256, 0, stream>>>(w1l, w1r, w2l, w2r, w3l, w3r,
                                   t1l, t1r, t2l, t2r, t3l, t3r);
  k_bin<<<BIN_B, 256, 0, stream>>>(ei, bcnt, bbuf);
  k_insert<<<NBUK, 256, 0, stream>>>(bcnt, bbuf, deg, ebuf);

  // --- layer 1: 64 -> (4 heads x 32), concat ---
  k_xmm<64, 128><<<XMM_B, 256, 0, stream>>>(x, t1l, t1r, b1l, b1r, A, B);
  k_gat<4><<<N / 4, 256, 0, stream>>>(A, B, a1, c1, deg, ebuf, Cb);

  // --- layer 2: 128 -> (2 heads x 32), concat ---
  k_xmm<128, 64><<<XMM_B, 256, 0, stream>>>(Cb, t2l, t2r, b2l, b2r, A, B);
  k_gat<2><<<N / 4, 256, 0, stream>>>(A, B, a2, c2, deg, ebuf, Cb);

  // --- layer 3: 64 -> (1 head x 32), mean over 1 head == identity ---
  k_xmm<64, 32><<<XMM_B, 256, 0, stream>>>(Cb, t3l, t3r, b3l, b3r, A, B);
  k_gat<1><<<N / 4, 256, 0, stream>>>(A, B, a3, c3, deg, ebuf, Cb);

  // --- MLP head + sigmoid/tanh ---
  k_mlp<<<(N + 255) / 256, 256, 0, stream>>>(Cb, wm1, bm1, wm2, bm2, outp);
}

// Round 8
// 392.626 us; speedup vs baseline: 1.3998x; 1.1122x over previous
//
#include <hip/hip_runtime.h>
#include <hip/hip_fp16.h>

// GATv2 x3 + MLP head on MI355X.
// R11: k_bin rewritten as block-local counting sort. R10 showed k_bin at
// 83us with VALU 0.9% / HBM 10% - idle machine, bound by 1.6M device-scope
// atomics (256 serial hits/counter) + 9x write amplification. Now: per-block
// LDS histogram (782 buckets) -> ONE global atomicAdd per (bucket,class) to
// reserve a range (153K atomics, 10x fewer, ~25 hits/counter) -> scatter at
// LDS-base+rank. Class striping kept (XCD-private sub-bucket tails -> full-
// line writebacks). k_insert/k_xmm/k_gat/k_mlp unchanged from R10.

constexpr int N = 100000;
constexpr int E = 1600000;
constexpr int S = 48;       // slots per node (cap; stores guarded)

constexpr int NBUK = (N + 127) >> 7;          // 782 buckets of 128 nodes
constexpr int BCAP = 384;                     // per (bucket, class) cap; mean 256
constexpr int EPB = 8192;                     // edges per bin block
constexpr int BIN_B = (E + EPB - 1) / EPB;    // 196 bin blocks
constexpr int XMM_B = (N + 63) / 64;          // xmm blocks (64 nodes each)

typedef _Float16 half8_t __attribute__((ext_vector_type(8)));
typedef _Float16 half4_t __attribute__((ext_vector_type(4)));
typedef _Float16 h2 __attribute__((ext_vector_type(2)));
typedef float f32x4 __attribute__((ext_vector_type(4)));

// ---------------- pass 1: block-local counting sort into (bucket,class) ----

__global__ __launch_bounds__(256) void k_bin(const int* __restrict__ ei,
                                             int* __restrict__ bcnt,
                                             unsigned* __restrict__ bbuf) {
  __shared__ int hist[NBUK];
  const int tid = threadIdx.x;
  const int cls = blockIdx.x & 7;   // maps ~1:1 to XCD by round-robin dispatch
  const int e0 = blockIdx.x * EPB;
  for (int i = tid; i < NBUK; i += 256) hist[i] = 0;
  __syncthreads();
  // phase 1: LDS histogram of dst buckets (block-private)
  #pragma unroll 4
  for (int j = 0; j < EPB / 256; ++j) {
    const int e = e0 + j * 256 + tid;
    if (e < E) atomicAdd(&hist[ei[E + e] >> 7], 1);
  }
  __syncthreads();
  // phase 2: reserve a contiguous range per bucket (one global atomic each)
  for (int i = tid; i < NBUK; i += 256) {
    const int h = hist[i];
    hist[i] = h ? atomicAdd(&bcnt[i * 8 + cls], h) : 0;
  }
  __syncthreads();
  // phase 3: scatter at base+rank (edge window is L2-hot from phase 1)
  #pragma unroll 4
  for (int j = 0; j < EPB / 256; ++j) {
    const int e = e0 + j * 256 + tid;
    if (e < E) {
      const int src = ei[e];
      const int dst = ei[E + e];
      const int b = dst >> 7;
      const int pos = atomicAdd(&hist[b], 1);   // LDS: base + local rank
      if (pos < BCAP)
        bbuf[(size_t)(b * 8 + cls) * BCAP + pos] =
            ((unsigned)(dst & 127) << 17) | (unsigned)src;
    }
  }
}

// ---------------- pass 2: per-bucket insert with LDS slot claims ------------
// Slot 0 of every node is the (deterministic) self-loop.

__global__ __launch_bounds__(256) void k_insert(const int* __restrict__ bcnt,
                                                const unsigned* __restrict__ bbuf,
                                                int* __restrict__ deg,
                                                int* __restrict__ ebuf) {
  __shared__ int cnt[128];
  const int b = blockIdx.x;
  const int tid = threadIdx.x;
  const int node0 = b * 128 + tid;
  if (tid < 128) {
    cnt[tid] = 1;                                   // self-loop occupies slot 0
    if (node0 < N) ebuf[node0 * S] = node0;
  }
  __syncthreads();
  #pragma unroll 1
  for (int c = 0; c < 8; ++c) {
    const int n = min(bcnt[b * 8 + c], BCAP);
    const unsigned* arr = bbuf + (size_t)(b * 8 + c) * BCAP;
    for (int i = tid; i < n; i += 256) {
      const unsigned ent = arr[i];
      const int dlo = (int)(ent >> 17);
      const int src = (int)(ent & 0x1FFFFu);
      const int pos = atomicAdd(&cnt[dlo], 1);   // LDS atomic, block-exclusive
      if (pos < S) ebuf[(b * 128 + dlo) * S + pos] = src;
    }
  }
  __syncthreads();
  if (tid < 128 && node0 < N) deg[node0] = cnt[tid];
}

// ---------------- weight prep: fp32 [K][M] -> fp16 transposed+swizzled ------
// WT[m][k] stored at m*K + (k ^ ((m&7)<<3))   (XOR on 8-half units = 16B)

template <int K, int M>
__device__ __forceinline__ void wprep_body(const float* __restrict__ src,
                                           __half* __restrict__ dst, int blk) {
  const int idx = blk * 256 + threadIdx.x;     // grid sized so idx < K*M
  const int k = idx / M;
  const int m = idx % M;
  ((_Float16*)dst)[m * K + (k ^ ((m & 7) << 3))] = (_Float16)src[idx];
}

__global__ __launch_bounds__(256) void k_wprep(
    const float* w1l, const float* w1r, const float* w2l, const float* w2r,
    const float* w3l, const float* w3r,
    __half* o1l, __half* o1r, __half* o2l, __half* o2r,
    __half* o3l, __half* o3r) {
  int b = blockIdx.x;                 // sizes: 4x32 blocks (8192) + 2x8 (2048)
  if      (b < 32)  wprep_body<64, 128>(w1l, o1l, b);
  else if (b < 64)  wprep_body<64, 128>(w1r, o1r, b - 32);
  else if (b < 96)  wprep_body<128, 64>(w2l, o2l, b - 64);
  else if (b < 128) wprep_body<128, 64>(w2r, o2r, b - 96);
  else if (b < 136) wprep_body<64, 32>(w3l, o3l, b - 128);
  else              wprep_body<64, 32>(w3r, o3r, b - 136);
}

// ---------------- MFMA transform: y = x[K] @ w[K,M] + b, L and R fused ------
// Block: 64 nodes, 4 waves; wave = 16 rows x M cols. fp16 in, fp32 acc,
// fp16 out. A: row=lane&15, k=(lane>>4)*8+j. B: col=lane&15 (from WT[M][K]).
// D: col=lane&15, row=(lane>>4)*4+r.

template <int K, int M>
__global__ __launch_bounds__(256) void k_xmm(const float* __restrict__ x,
                                             const __half* __restrict__ wtl,
                                             const __half* __restrict__ wtr,
                                             const float* __restrict__ bl,
                                             const float* __restrict__ br,
                                             __half* __restrict__ Aout,
                                             __half* __restrict__ Bout) {
  constexpr int XSZ = 64 * K;        // halfs
  constexpr int WSZ = M * K;         // halfs per weight matrix
  constexpr int KS = K / 32;         // MFMA k-steps
  constexpr int CT = M / 16;         // col tiles
  __shared__ _Float16 pool[XSZ + 2 * WSZ];

  const int tid = threadIdx.x;
  const int node0 = blockIdx.x * 64;

  // --- stage X tile (fp32 -> fp16, swizzled) ---
  for (int i = tid; i < 64 * (K / 4); i += 256) {
    const int row = i / (K / 4);
    const int c4 = i % (K / 4);
    const int grow = min(node0 + row, N - 1);
    float4 v = reinterpret_cast<const float4*>(x)[(size_t)grow * (K / 4) + c4];
    const int k0 = c4 * 4;
    const int hidx = row * K + ((k0) ^ ((row & 7) << 3));
    *reinterpret_cast<half4_t*>(&pool[hidx]) =
        (half4_t){(_Float16)v.x, (_Float16)v.y, (_Float16)v.z, (_Float16)v.w};
  }
  // --- stage WT_l, WT_r (linear fp16 copy; already transposed+swizzled) ---
  for (int i = tid; i < WSZ / 8; i += 256) {
    reinterpret_cast<uint4*>(&pool[XSZ])[i] =
        reinterpret_cast<const uint4*>(wtl)[i];
    reinterpret_cast<uint4*>(&pool[XSZ + WSZ])[i] =
        reinterpret_cast<const uint4*>(wtr)[i];
  }
  __syncthreads();

  const int lane = tid & 63;
  const int wid = tid >> 6;
  const int r0 = wid * 16;

  // --- A fragments (shared across col tiles and both sides) ---
  half8_t af[KS];
  #pragma unroll
  for (int ks = 0; ks < KS; ++ks) {
    const int row = r0 + (lane & 15);
    const int k0 = ks * 32 + (lane >> 4) * 8;
    af[ks] = *reinterpret_cast<const half8_t*>(
        &pool[row * K + (k0 ^ ((row & 7) << 3))]);
  }

  f32x4 accl[CT], accr[CT];
  #pragma unroll
  for (int ct = 0; ct < CT; ++ct) {
    accl[ct] = (f32x4){0.f, 0.f, 0.f, 0.f};
    accr[ct] = (f32x4){0.f, 0.f, 0.f, 0.f};
  }

  #pragma unroll
  for (int ct = 0; ct < CT; ++ct) {
    #pragma unroll
    for (int ks = 0; ks < KS; ++ks) {
      const int col = ct * 16 + (lane & 15);
      const int k0 = ks * 32 + (lane >> 4) * 8;
      const int hb = col * K + (k0 ^ ((col & 7) << 3));
      half8_t bfl = *reinterpret_cast<const half8_t*>(&pool[XSZ + hb]);
      accl[ct] = __builtin_amdgcn_mfma_f32_16x16x32_f16(af[ks], bfl, accl[ct], 0, 0, 0);
      half8_t bfr = *reinterpret_cast<const half8_t*>(&pool[XSZ + WSZ + hb]);
      accr[ct] = __builtin_amdgcn_mfma_f32_16x16x32_f16(af[ks], bfr, accr[ct], 0, 0, 0);
    }
  }

  // --- epilogue: D -> LDS (unswizzled) -> coalesced global stores ---
  __syncthreads();   // staging regions dead; D region aliases pool[0..64*M)
  #pragma unroll
  for (int ct = 0; ct < CT; ++ct) {
    const int col = ct * 16 + (lane & 15);
    const float bb = bl[col];
    #pragma unroll
    for (int r = 0; r < 4; ++r) {
      const int row = r0 + (lane >> 4) * 4 + r;
      pool[row * M + col] = (_Float16)(accl[ct][r] + bb);
    }
  }
  __syncthreads();
  for (int i = tid; i < 64 * (M / 8); i += 256) {
    const int row = i / (M / 8);
    const int j = i % (M / 8);
    const int g = node0 + row;
    if (g < N)
      reinterpret_cast<uint4*>(Aout + (size_t)g * M)[j] =
          reinterpret_cast<uint4*>(&pool[row * M])[j];
  }
  __syncthreads();
  #pragma unroll
  for (int ct = 0; ct < CT; ++ct) {
    const int col = ct * 16 + (lane & 15);
    const float bb = br[col];
    #pragma unroll
    for (int r = 0; r < 4; ++r) {
      const int row = r0 + (lane >> 4) * 4 + r;
      pool[row * M + col] = (_Float16)(accr[ct][r] + bb);
    }
  }
  __syncthreads();
  for (int i = tid; i < 64 * (M / 8); i += 256) {
    const int row = i / (M / 8);
    const int j = i % (M / 8);
    const int g = node0 + row;
    if (g < N)
      reinterpret_cast<uint4*>(Bout + (size_t)g * M)[j] =
          reinterpret_cast<uint4*>(&pool[row * M])[j];
  }
}

// ---------------- GATv2 aggregation: one wave per dst node ----------------
// Lane holds 8 fp16 features = one 16B gather per edge. Packed fp16 score
// path (pk_add/pk_mul/pk_max + v_dot2_f32_f16); fp32 accumulator via
// mixed-precision fma. One head == one 4-lane quad: reduce = 2 DPP adds.

template <int CTRL>
__device__ __forceinline__ float dpp_add(float x) {
  return x + __builtin_bit_cast(float,
      __builtin_amdgcn_update_dpp(0, __builtin_bit_cast(int, x),
                                  CTRL, 0xF, 0xF, true));
}

template <int H>
__global__ __launch_bounds__(256) void k_gat(const __half* __restrict__ xl,
                                             const __half* __restrict__ xr,
                                             const float* __restrict__ att,
                                             const float* __restrict__ bias,
                                             const int* __restrict__ deg,
                                             const int* __restrict__ ebuf,
                                             float* __restrict__ out) {
  constexpr int F = H * 32;
  constexpr int F8 = F / 8;        // 16B chunks (8 halfs) per row
  constexpr int F4 = F / 4;        // float4 per fp32 out row
  constexpr int LPE = F8;          // lanes per edge: 16 / 8 / 4
  constexpr int EPI = 64 / LPE;    // edges per iteration: 4 / 8 / 16
  constexpr float LOG2E = 1.44269504088896f;
  const int lane = threadIdx.x & 63;
  const int node = (blockIdx.x * blockDim.x + threadIdx.x) >> 6;
  if (node >= N) return;
  const int li = lane & (LPE - 1);  // 16B chunk index within row
  const int eg = lane / LPE;

  const uint4* xl4 = reinterpret_cast<const uint4*>(xl);
  const uint4* xr4 = reinterpret_cast<const uint4*>(xr);

  // xi: 8 fp16 channels kept packed
  const uint4 xiraw = xr4[(unsigned)node * F8 + li];
  h2 xi2[4];
  xi2[0] = __builtin_bit_cast(h2, xiraw.x);
  xi2[1] = __builtin_bit_cast(h2, xiraw.y);
  xi2[2] = __builtin_bit_cast(h2, xiraw.z);
  xi2[3] = __builtin_bit_cast(h2, xiraw.w);

  // att: fp32 -> pre-scaled fp16 pairs
  const float4 at0 = reinterpret_cast<const float4*>(att)[li * 2];
  const float4 at1 = reinterpret_cast<const float4*>(att)[li * 2 + 1];
  h2 at2[4];
  at2[0] = (h2){(_Float16)(at0.x * LOG2E), (_Float16)(at0.y * LOG2E)};
  at2[1] = (h2){(_Float16)(at0.z * LOG2E), (_Float16)(at0.w * LOG2E)};
  at2[2] = (h2){(_Float16)(at1.x * LOG2E), (_Float16)(at1.y * LOG2E)};
  at2[3] = (h2){(_Float16)(at1.z * LOG2E), (_Float16)(at1.w * LOG2E)};
  const h2 c02 = {(_Float16)0.2f, (_Float16)0.2f};

  float4 acc0 = make_float4(0.f, 0.f, 0.f, 0.f);
  float4 acc1 = make_float4(0.f, 0.f, 0.f, 0.f);
  float l = 0.f;

  const int* row = ebuf + node * S;
  const int dn = min(deg[node], S);   // deg >= 1 (self loop)
  const int last = dn - 1;
  const int iters = (dn + EPI - 1) / EPI;

  auto process = [&](const uint4& raw, bool valid) {
    h2 xj0 = __builtin_bit_cast(h2, raw.x);
    h2 xj1 = __builtin_bit_cast(h2, raw.y);
    h2 xj2 = __builtin_bit_cast(h2, raw.z);
    h2 xj3 = __builtin_bit_cast(h2, raw.w);
    float t = 0.f;
    h2 v;
    v = xi2[0] + xj0; v = __builtin_elementwise_max(v, v * c02);
    t = __builtin_amdgcn_fdot2(at2[0], v, t, false);
    v = xi2[1] + xj1; v = __builtin_elementwise_max(v, v * c02);
    t = __builtin_amdgcn_fdot2(at2[1], v, t, false);
    v = xi2[2] + xj2; v = __builtin_elementwise_max(v, v * c02);
    t = __builtin_amdgcn_fdot2(at2[2], v, t, false);
    v = xi2[3] + xj3; v = __builtin_elementwise_max(v, v * c02);
    t = __builtin_amdgcn_fdot2(at2[3], v, t, false);
    // head = one 4-lane quad: butterfly via quad_perm DPP (VALU, no LDS pipe)
    t = dpp_add<0xB1>(t);   // xor 1: [1,0,3,2]
    t = dpp_add<0x4E>(t);   // xor 2: [2,3,0,1]
    float pm = valid ? exp2f(t) : 0.f;
    l += pm;
    // fp32 acc; (float)h * f + acc folds to v_fma_mix_f32
    acc0.x = fmaf(pm, (float)xj0[0], acc0.x);
    acc0.y = fmaf(pm, (float)xj0[1], acc0.y);
    acc0.z = fmaf(pm, (float)xj1[0], acc0.z);
    acc0.w = fmaf(pm, (float)xj1[1], acc0.w);
    acc1.x = fmaf(pm, (float)xj2[0], acc1.x);
    acc1.y = fmaf(pm, (float)xj2[1], acc1.y);
    acc1.z = fmaf(pm, (float)xj3[0], acc1.z);
    acc1.w = fmaf(pm, (float)xj3[1], acc1.w);
  };

  // pipeline warm-up: src prefetched 2 iterations ahead, gather 1 ahead
  int i = eg;
  bool vA = i < dn;
  int s0 = row[min(i, last)];
  i += EPI;
  uint4 xjA = xl4[(unsigned)s0 * F8 + li];
  bool vB = i < dn;
  int sN = row[min(i, last)];
  i += EPI;
  uint4 xjB;

  for (int it = 0; it < iters; it += 2) {
    // ---- phase A: consume (xjA, vA) = iteration it ----
    xjB = xl4[(unsigned)sN * F8 + li];             // gather it+1
    bool vn = i < dn;
    sN = row[min(i, last)];                        // src it+2
    i += EPI;
    process(xjA, vA);
    vA = vn;
    // ---- phase B: consume (xjB, vB) = iteration it+1 ----
    xjA = xl4[(unsigned)sN * F8 + li];             // gather it+2
    vn = i < dn;
    sN = row[min(i, last)];                        // src it+3
    i += EPI;
    process(xjB, vB);
    vB = vn;
  }

  // combine the EPI edge slots (once per node)
  #pragma unroll
  for (int ofs = LPE; ofs < 64; ofs <<= 1) {
    acc0.x += __shfl_xor(acc0.x, ofs);
    acc0.y += __shfl_xor(acc0.y, ofs);
    acc0.z += __shfl_xor(acc0.z, ofs);
    acc0.w += __shfl_xor(acc0.w, ofs);
    acc1.x += __shfl_xor(acc1.x, ofs);
    acc1.y += __shfl_xor(acc1.y, ofs);
    acc1.z += __shfl_xor(acc1.z, ofs);
    acc1.w += __shfl_xor(acc1.w, ofs);
    l      += __shfl_xor(l, ofs);
  }

  if (lane < LPE) {
    const float inv = 1.f / (l + 1e-16f);
    const float4 bv0 = reinterpret_cast<const float4*>(bias)[li * 2];
    const float4 bv1 = reinterpret_cast<const float4*>(bias)[li * 2 + 1];
    float4 r0, r1;
    r0.x = fmaxf(acc0.x * inv + bv0.x, 0.f);
    r0.y = fmaxf(acc0.y * inv + bv0.y, 0.f);
    r0.z = fmaxf(acc0.z * inv + bv0.z, 0.f);
    r0.w = fmaxf(acc0.w * inv + bv0.w, 0.f);
    r1.x = fmaxf(acc1.x * inv + bv1.x, 0.f);
    r1.y = fmaxf(acc1.y * inv + bv1.y, 0.f);
    r1.z = fmaxf(acc1.z * inv + bv1.z, 0.f);
    r1.w = fmaxf(acc1.w * inv + bv1.w, 0.f);
    float4* op = reinterpret_cast<float4*>(out) + (unsigned)node * F4 + li * 2;
    op[0] = r0;
    op[1] = r1;
  }
}

// ---------------- MLP head + output transforms ----------------

__global__ __launch_bounds__(256) void k_mlp(const float* __restrict__ h,
                                             const float* __restrict__ wm1,
                                             const float* __restrict__ bm1,
                                             const float* __restrict__ wm2,
                                             const float* __restrict__ bm2,
                                             float* __restrict__ out) {
  __shared__ float w1[512], b1[16], w2[32], b2[2];
  const int tid = threadIdx.x;
  for (int i = tid; i < 512; i += 256) w1[i] = wm1[i];
  if (tid < 16) b1[tid] = bm1[tid];
  if (tid < 32) w2[tid] = wm2[tid];
  if (tid < 2)  b2[tid] = bm2[tid];
  __syncthreads();
  const int node = blockIdx.x * blockDim.x + tid;
  if (node >= N) return;
  float hv[32];
  const float* hp = h + (size_t)node * 32;
  #pragma unroll
  for (int k = 0; k < 8; ++k) {
    float4 v = reinterpret_cast<const float4*>(hp)[k];
    hv[4 * k] = v.x; hv[4 * k + 1] = v.y; hv[4 * k + 2] = v.z; hv[4 * k + 3] = v.w;
  }
  float r0 = b2[0], r1 = b2[1];
  #pragma unroll
  for (int j = 0; j < 16; ++j) {
    float a = b1[j];
    #pragma unroll
    for (int k = 0; k < 32; ++k) a += hv[k] * w1[k * 16 + j];
    a = fmaxf(a, 0.f);
    r0 += a * w2[j * 2];
    r1 += a * w2[j * 2 + 1];
  }
  float vm = 1.f / (1.f + __expf(-r0)) + 0.5f;
  float va = tanhf(r1) * 180.f;
  out[(size_t)node * 2]     = vm;
  out[(size_t)node * 2 + 1] = va;
}

// ---------------- launch ----------------

extern "C" void kernel_launch(void* const* d_in, const int* in_sizes, int n_in,
                              void* d_out, int out_size, void* d_ws, size_t ws_size,
                              hipStream_t stream) {
  const float* x   = (const float*)d_in[0];
  const int*   ei  = (const int*)d_in[1];
  const float* w1l = (const float*)d_in[2];
  const float* b1l = (const float*)d_in[3];
  const float* w1r = (const float*)d_in[4];
  const float* b1r = (const float*)d_in[5];
  const float* a1  = (const float*)d_in[6];
  const float* c1  = (const float*)d_in[7];
  const float* w2l = (const float*)d_in[8];
  const float* b2l = (const float*)d_in[9];
  const float* w2r = (const float*)d_in[10];
  const float* b2r = (const float*)d_in[11];
  const float* a2  = (const float*)d_in[12];
  const float* c2  = (const float*)d_in[13];
  const float* w3l = (const float*)d_in[14];
  const float* b3l = (const float*)d_in[15];
  const float* w3r = (const float*)d_in[16];
  const float* b3r = (const float*)d_in[17];
  const float* a3  = (const float*)d_in[18];
  const float* c3  = (const float*)d_in[19];
  const float* wm1 = (const float*)d_in[20];
  const float* bm1 = (const float*)d_in[21];
  const float* wm2 = (const float*)d_in[22];
  const float* bm2 = (const float*)d_in[23];
  float* outp = (float*)d_out;
  (void)in_sizes; (void)n_in; (void)out_size; (void)ws_size;

  char* ws = (char*)d_ws;
  size_t o = 0;
  auto take = [&](size_t bytes) {
    char* p = ws + o;
    o = (o + bytes + 255) & ~(size_t)255;
    return p;
  };
  int* deg       = (int*)take((size_t)N * sizeof(int));
  int* ebuf      = (int*)take((size_t)N * S * sizeof(int));
  int* bcnt      = (int*)take((size_t)NBUK * 8 * sizeof(int));
  unsigned* bbuf = (unsigned*)take((size_t)NBUK * 8 * BCAP * sizeof(unsigned));
  __half* A      = (__half*)take((size_t)N * 128 * sizeof(__half));  // xl (fp16)
  __half* B      = (__half*)take((size_t)N * 128 * sizeof(__half));  // xr (fp16)
  float* Cb      = (float*)take((size_t)N * 128 * sizeof(float));    // h (layer out)
  __half* t1l    = (__half*)take(128 * 64 * sizeof(__half));   // WT fp16 swizzled
  __half* t1r    = (__half*)take(128 * 64 * sizeof(__half));
  __half* t2l    = (__half*)take(64 * 128 * sizeof(__half));
  __half* t2r    = (__half*)take(64 * 128 * sizeof(__half));
  __half* t3l    = (__half*)take(32 * 64 * sizeof(__half));
  __half* t3r    = (__half*)take(32 * 64 * sizeof(__half));

  // --- weight prep + graph build (shared across all 3 layers) ---
  hipMemsetAsync(bcnt, 0, (size_t)NBUK * 8 * sizeof(int), stream);
  k_wprep<<<144, 256, 0, stream>>>(w1l, w1r, w2l, w2r, w3l, w3r,
                                   t1l, t1r, t2l, t2r, t3l, t3r);
  k_bin<<<BIN_B, 256, 0, stream>>>(ei, bcnt, bbuf);
  k_insert<<<NBUK, 256, 0, stream>>>(bcnt, bbuf, deg, ebuf);

  // --- layer 1: 64 -> (4 heads x 32), concat ---
  k_xmm<64, 128><<<XMM_B, 256, 0, stream>>>(x, t1l, t1r, b1l, b1r, A, B);
  k_gat<4><<<N / 4, 256, 0, stream>>>(A, B, a1, c1, deg, ebuf, Cb);

  // --- layer 2: 128 -> (2 heads x 32), concat ---
  k_xmm<128, 64><<<XMM_B, 256, 0, stream>>>(Cb, t2l, t2r, b2l, b2r, A, B);
  k_gat<2><<<N / 4, 256, 0, stream>>>(A, B, a2, c2, deg, ebuf, Cb);

  // --- layer 3: 64 -> (1 head x 32), mean over 1 head == identity ---
  k_xmm<64, 32><<<XMM_B, 256, 0, stream>>>(Cb, t3l, t3r, b3l, b3r, A, B);
  k_gat<1><<<N / 4, 256, 0, stream>>>(A, B, a3, c3, deg, ebuf, Cb);

  // --- MLP head + sigmoid/tanh ---
  k_mlp<<<(N + 255) / 256, 256, 0, stream>>>(Cb, wm1, bm1, wm2, bm2, outp);
}